// Round 6
// baseline (1017.518 us; speedup 1.0000x reference)
//
#include <hip/hip_runtime.h>

#define DEV __device__ __forceinline__

static const int NN = 100000;
static const int EE = 1000000;
static const int KB_ = 13;        // source buckets per row (src>>13 -> 0..12)
static const int SHIFT_ = 13;     // 8192-node bucket = 1.05 MB of x rows
static const int KN = KB_ * NN;   // key space per graph

typedef unsigned int uv4 __attribute__((ext_vector_type(4)));

DEV float bf2f(unsigned int h) {
    unsigned int u = h << 16;
    float f;
    __builtin_memcpy(&f, &u, 4);
    return f;
}
DEV unsigned short f2bf(float f) {  // round-to-nearest-even
    unsigned int u;
    __builtin_memcpy(&u, &f, 4);
    u = u + 0x7FFFu + ((u >> 16) & 1u);
    return (unsigned short)(u >> 16);
}
DEV unsigned int pk2(float a, float b) {
    return (unsigned int)f2bf(a) | ((unsigned int)f2bf(b) << 16);
}
DEV void unpack8(uint4 u, float* v) {
    v[0] = bf2f(u.x & 0xffffu); v[1] = bf2f(u.x >> 16);
    v[2] = bf2f(u.y & 0xffffu); v[3] = bf2f(u.y >> 16);
    v[4] = bf2f(u.z & 0xffffu); v[5] = bf2f(u.z >> 16);
    v[6] = bf2f(u.w & 0xffffu); v[7] = bf2f(u.w >> 16);
}
DEV void store_row64(unsigned short* __restrict__ out, int r, const float* acc, bool relu) {
    uint4* o = reinterpret_cast<uint4*>(out + (size_t)r * 64);
#pragma unroll
    for (int c = 0; c < 8; c++) {
        float a[8];
#pragma unroll
        for (int i = 0; i < 8; i++) {
            float x = acc[c * 8 + i];
            a[i] = relu ? fmaxf(x, 0.0f) : x;
        }
        uint4 u;
        u.x = pk2(a[0], a[1]); u.y = pk2(a[2], a[3]);
        u.z = pk2(a[4], a[5]); u.w = pk2(a[6], a[7]);
        o[c] = u;
    }
}

// ---------------- CSR build, bucket-sorted rows (dual-graph via blockIdx.y) ----------------
// key = dst*13 + (src>>13): row-major by dst, edges within a row grouped by src bucket.
__global__ __launch_bounds__(256) void k_count_dual(const int* __restrict__ s0, const int* __restrict__ s1,
                                                    int* __restrict__ c0, int* __restrict__ c1,
                                                    int* __restrict__ p0, int* __restrict__ p1, int e) {
    int g = blockIdx.y;
    const int* src = g ? s1 : s0;
    const int* dst = src + e;
    int* cnt = g ? c1 : c0;
    int* pos = g ? p1 : p0;
    int i = blockIdx.x * blockDim.x + threadIdx.x;
    if (i >= e) return;
    int key = dst[i] * KB_ + (src[i] >> SHIFT_);
    pos[i] = atomicAdd(&cnt[key], 1);
}
// blocked scan over KN keys: 8192 elems/block (32/thread)
__global__ __launch_bounds__(256) void k_scan_partial_dual(const int* __restrict__ c0, const int* __restrict__ c1,
                                                           int* __restrict__ p0, int* __restrict__ p1, int n) {
    int g = blockIdx.y;
    const int* cnt = g ? c1 : c0;
    int* partial = g ? p1 : p0;
    __shared__ int lds[256];
    int t = threadIdx.x;
    int base = blockIdx.x * 8192 + t * 32;
    int s = 0;
#pragma unroll 8
    for (int i = 0; i < 32; i++) {
        int idx = base + i;
        s += (idx < n) ? cnt[idx] : 0;
    }
    lds[t] = s;
    __syncthreads();
    for (int off = 128; off > 0; off >>= 1) {
        if (t < off) lds[t] += lds[t + off];
        __syncthreads();
    }
    if (t == 0) partial[blockIdx.x] = lds[0];
}
__global__ __launch_bounds__(256) void k_scan_single_dual(int* __restrict__ p0, int* __restrict__ p1, int B) {
    int g = blockIdx.y;
    int* partial = g ? p1 : p0;
    __shared__ int lds[256];
    int t = threadIdx.x;
    int v = (t < B) ? partial[t] : 0;
    lds[t] = v;
    __syncthreads();
    for (int off = 1; off < 256; off <<= 1) {
        int x = (t >= off) ? lds[t - off] : 0;
        __syncthreads();
        lds[t] += x;
        __syncthreads();
    }
    if (t < B) partial[t] = lds[t] - v;  // exclusive
}
__global__ __launch_bounds__(256) void k_scan_write_dual(const int* __restrict__ c0, const int* __restrict__ c1,
                                                         const int* __restrict__ p0, const int* __restrict__ p1,
                                                         int* __restrict__ r0, int* __restrict__ r1,
                                                         int n, int total) {
    int g = blockIdx.y;
    const int* cnt = g ? c1 : c0;
    const int* partial = g ? p1 : p0;
    int* rowptr = g ? r1 : r0;
    __shared__ int lds[256];
    int t = threadIdx.x;
    int base = blockIdx.x * 8192 + t * 32;
    int v[32];
    int s = 0;
#pragma unroll 8
    for (int i = 0; i < 32; i++) {
        int idx = base + i;
        v[i] = (idx < n) ? cnt[idx] : 0;
        s += v[i];
    }
    lds[t] = s;
    __syncthreads();
    int mine = s;
    for (int off = 1; off < 256; off <<= 1) {
        int x = (t >= off) ? lds[t - off] : 0;
        __syncthreads();
        lds[t] += x;
        __syncthreads();
    }
    int run = lds[t] - mine + partial[blockIdx.x];
#pragma unroll 8
    for (int i = 0; i < 32; i++) {
        int idx = base + i;
        if (idx < n) rowptr[idx] = run;
        run += v[i];
    }
    if (blockIdx.x == 0 && t == 0) rowptr[n] = total;
}
// dinv from rowptr totals (deg = row span)
__global__ __launch_bounds__(256) void k_dinv_dual(const int* __restrict__ r0, const int* __restrict__ r1,
                                                   float* __restrict__ v0, float* __restrict__ v1, int n) {
    int g = blockIdx.y;
    const int* rowptr = g ? r1 : r0;
    float* dinv = g ? v1 : v0;
    int d = blockIdx.x * blockDim.x + threadIdx.x;
    if (d < n) {
        int deg = rowptr[(d + 1) * KB_] - rowptr[d * KB_];
        dinv[d] = rsqrtf((float)deg + 1.0f);
    }
}
// atomic-free fill; normal stores (L2 write-allocate merges 8B records)
__global__ __launch_bounds__(256) void k_fill_dual(const int* __restrict__ s0, const int* __restrict__ s1,
                                                   const int* __restrict__ q0, const int* __restrict__ q1,
                                                   const float* __restrict__ v0, const float* __restrict__ v1,
                                                   const int* __restrict__ r0, const int* __restrict__ r1,
                                                   int2* __restrict__ e0, int2* __restrict__ e1, int e) {
    int g = blockIdx.y;
    const int* src = g ? s1 : s0;
    const int* dstv = src + e;
    const int* pos = g ? q1 : q0;
    const float* dinv = g ? v1 : v0;
    const int* rowptr = g ? r1 : r0;
    int2* ec = g ? e1 : e0;
    int i = blockIdx.x * blockDim.x + threadIdx.x;
    if (i >= e) return;
    int s = src[i], d = dstv[i];
    int idx = rowptr[d * KB_ + (s >> SHIFT_)] + pos[i];
    ec[idx] = make_int2(s, __float_as_int(dinv[s] * dinv[d]));
}

// ---------------- fused encoder MLP: relu(x@w1+b1)@w2+b2 -> bf16  (dual) ----------------
__global__ __launch_bounds__(256) void k_enc_dual(const float* __restrict__ x0, const float* __restrict__ x1,
                                                  const float* __restrict__ w1a, const float* __restrict__ w1b,
                                                  const float* __restrict__ b1a, const float* __restrict__ b1b,
                                                  const float* __restrict__ w2a, const float* __restrict__ w2b,
                                                  const float* __restrict__ b2a, const float* __restrict__ b2b,
                                                  unsigned short* __restrict__ y0, unsigned short* __restrict__ y1,
                                                  int n) {
    int g = blockIdx.y;
    const float* x = g ? x1 : x0;
    const float* w1 = g ? w1b : w1a;
    const float* b1 = g ? b1b : b1a;
    const float* w2 = g ? w2b : w2a;
    const float* b2 = g ? b2b : b2a;
    unsigned short* out = g ? y1 : y0;
    int r = blockIdx.x * blockDim.x + threadIdx.x;
    if (r >= n) return;
    float4 xv = reinterpret_cast<const float4*>(x)[r];
    float xk[4] = {xv.x, xv.y, xv.z, xv.w};
    float h2[64];
#pragma unroll
    for (int j = 0; j < 64; j++) h2[j] = b2[j];
#pragma unroll
    for (int c = 0; c < 8; c++) {  // h1 in chunks of 8
        float h[8];
#pragma unroll
        for (int i = 0; i < 8; i++) h[i] = b1[c * 8 + i];
#pragma unroll
        for (int k = 0; k < 4; k++) {
#pragma unroll
            for (int i = 0; i < 8; i++) h[i] = fmaf(xk[k], w1[k * 64 + c * 8 + i], h[i]);
        }
#pragma unroll
        for (int i = 0; i < 8; i++) h[i] = fmaxf(h[i], 0.0f);
#pragma unroll
        for (int i = 0; i < 8; i++) {
            const float* wr = w2 + (c * 8 + i) * 64;
#pragma unroll
            for (int j = 0; j < 64; j++) h2[j] = fmaf(h[i], wr[j], h2[j]);
        }
    }
    store_row64(out, r, h2, false);
}

// ---------------- fused GCN layer: y = relu( (A_hat x) W + b )  (dual) ----------------
DEV void fma_edge(float* acc, uint4 u, float c) {
    float v[8];
    unpack8(u, v);
#pragma unroll
    for (int i = 0; i < 8; i++) acc[i] = fmaf(v[i], c, acc[i]);
}
// N divisible by 32 and grid.x == N/32: every thread owns a valid node (no guards,
// so the per-bucket __syncthreads is uniform).
__global__ __launch_bounds__(256) void k_conv_dual(const unsigned short* __restrict__ x0,
                                                   const unsigned short* __restrict__ x1,
                                                   const int2* __restrict__ ec0, const int2* __restrict__ ec1,
                                                   const int* __restrict__ r0, const int* __restrict__ r1,
                                                   const float* __restrict__ v0, const float* __restrict__ v1,
                                                   const float* __restrict__ w0, const float* __restrict__ w1,
                                                   const float* __restrict__ b0, const float* __restrict__ b1,
                                                   unsigned short* __restrict__ y0, unsigned short* __restrict__ y1) {
    int g = blockIdx.y;
    const unsigned short* x = g ? x1 : x0;
    const int2* ec = g ? ec1 : ec0;
    const int* rowptr = g ? r1 : r0;
    const float* dinv = g ? v1 : v0;
    const float* w = g ? w1 : w0;
    const float* b = g ? b1 : b0;
    unsigned short* y = g ? y1 : y0;

    __shared__ float agg[32][68];  // pad 64->68: phase-2 reads conflict-free

    int t = threadIdx.x;
    int cl = t >> 3;   // local node 0..31
    int ln = t & 7;    // feature-octet lane
    int node = blockIdx.x * 32 + cl;
    int fbase = ln * 8;
    float acc[8];
    {
        float d = dinv[node];
        float d2 = d * d;
        uint4 su = *reinterpret_cast<const uint4*>(x + (size_t)node * 64 + fbase);
        float sv[8];
        unpack8(su, sv);
#pragma unroll
        for (int i = 0; i < 8; i++) acc[i] = sv[i] * d2;
    }
    int kb = node * KB_;
    int e = rowptr[kb];  // running cursor; bucket ends are rowptr[kb+p+1]
#pragma unroll 1
    for (int p = 0; p < KB_; p++) {
        int e_end = rowptr[kb + p + 1];
        for (; e + 2 <= e_end; e += 2) {
            const long long* ep = reinterpret_cast<const long long*>(ec + e);
            long long q0 = __builtin_nontemporal_load(ep + 0);
            long long q1 = __builtin_nontemporal_load(ep + 1);
            int s0 = (int)q0, s1 = (int)q1;
            uint4 u0 = *reinterpret_cast<const uint4*>(x + (size_t)s0 * 64 + fbase);
            uint4 u1 = *reinterpret_cast<const uint4*>(x + (size_t)s1 * 64 + fbase);
            fma_edge(acc, u0, __int_as_float((int)(q0 >> 32)));
            fma_edge(acc, u1, __int_as_float((int)(q1 >> 32)));
        }
        if (e < e_end) {
            long long q0 = __builtin_nontemporal_load(reinterpret_cast<const long long*>(ec + e));
            int s0 = (int)q0;
            uint4 u0 = *reinterpret_cast<const uint4*>(x + (size_t)s0 * 64 + fbase);
            fma_edge(acc, u0, __int_as_float((int)(q0 >> 32)));
            e = e_end;
        }
        __syncthreads();  // keep the block phase-aligned on the same src bucket
    }
#pragma unroll
    for (int i = 0; i < 8; i += 4) {
        *reinterpret_cast<float4*>(&agg[cl][fbase + i]) = make_float4(acc[i], acc[i + 1], acc[i + 2], acc[i + 3]);
    }
    __syncthreads();

    // phase 2: out[fbase..fbase+8) = b + sum_k agg[cl][k] * W[k][fbase..]
    float out[8];
#pragma unroll
    for (int i = 0; i < 8; i++) out[i] = b[fbase + i];
#pragma unroll 4
    for (int k4 = 0; k4 < 16; k4++) {
        float4 av = *reinterpret_cast<const float4*>(&agg[cl][k4 * 4]);
        float a[4] = {av.x, av.y, av.z, av.w};
#pragma unroll
        for (int kk = 0; kk < 4; kk++) {
            const float4* wr = reinterpret_cast<const float4*>(w + (k4 * 4 + kk) * 64 + fbase);
            float4 wv0 = wr[0], wv1 = wr[1];
            out[0] = fmaf(a[kk], wv0.x, out[0]);
            out[1] = fmaf(a[kk], wv0.y, out[1]);
            out[2] = fmaf(a[kk], wv0.z, out[2]);
            out[3] = fmaf(a[kk], wv0.w, out[3]);
            out[4] = fmaf(a[kk], wv1.x, out[4]);
            out[5] = fmaf(a[kk], wv1.y, out[5]);
            out[6] = fmaf(a[kk], wv1.z, out[6]);
            out[7] = fmaf(a[kk], wv1.w, out[7]);
        }
    }
    uv4 ou;
    float r[8];
#pragma unroll
    for (int i = 0; i < 8; i++) r[i] = fmaxf(out[i], 0.0f);
    ou.x = pk2(r[0], r[1]); ou.y = pk2(r[2], r[3]); ou.z = pk2(r[4], r[5]); ou.w = pk2(r[6], r[7]);
    __builtin_nontemporal_store(ou, reinterpret_cast<uv4*>(y + (size_t)node * 64 + fbase));
}

// ---------------- fused tail: concat-MLP + both heads ----------------
__global__ __launch_bounds__(256) void k_tail(const unsigned short* __restrict__ F,
                                              const unsigned short* __restrict__ S,
                                              const float* __restrict__ w1, const float* __restrict__ b1,
                                              const float* __restrict__ w2, const float* __restrict__ b2,
                                              const float* __restrict__ ow, const float* __restrict__ ob,
                                              const float* __restrict__ cw, const float* __restrict__ cb,
                                              float* __restrict__ out, int n) {
    int r = blockIdx.x * blockDim.x + threadIdx.x;
    if (r >= n) return;
    float h1[64];
#pragma unroll
    for (int j = 0; j < 64; j++) h1[j] = b1[j];
    const uint4* Fr = reinterpret_cast<const uint4*>(F + (size_t)r * 64);
    const uint4* Sr = reinterpret_cast<const uint4*>(S + (size_t)r * 64);
#pragma unroll 1
    for (int k0 = 0; k0 < 8; k0++) {
        uint4 u = Fr[k0];
        float v[8];
        unpack8(u, v);
        const float* wk = w1 + k0 * 8 * 64;
#pragma unroll
        for (int i = 0; i < 8; i++) {
#pragma unroll
            for (int j = 0; j < 64; j++) h1[j] = fmaf(v[i], wk[i * 64 + j], h1[j]);
        }
    }
#pragma unroll 1
    for (int k0 = 0; k0 < 8; k0++) {
        uint4 u = Sr[k0];
        float v[8];
        unpack8(u, v);
        const float* wk = w1 + (64 + k0 * 8) * 64;
#pragma unroll
        for (int i = 0; i < 8; i++) {
#pragma unroll
            for (int j = 0; j < 64; j++) h1[j] = fmaf(v[i], wk[i * 64 + j], h1[j]);
        }
    }
#pragma unroll
    for (int j = 0; j < 64; j++) h1[j] = fmaxf(h1[j], 0.0f);

    float nf[32];
#pragma unroll
    for (int j = 0; j < 32; j++) nf[j] = ob[j];
    float nt0 = cb[0], nt1 = cb[1];
#pragma unroll 1
    for (int c = 0; c < 8; c++) {  // h2 in chunks of 8
        float h2[8];
#pragma unroll
        for (int i = 0; i < 8; i++) h2[i] = b2[c * 8 + i];
#pragma unroll
        for (int k = 0; k < 64; k++) {
            const float* wr = w2 + k * 64 + c * 8;
#pragma unroll
            for (int i = 0; i < 8; i++) h2[i] = fmaf(h1[k], wr[i], h2[i]);
        }
#pragma unroll
        for (int i = 0; i < 8; i++) {
            int kk = c * 8 + i;
#pragma unroll
            for (int j = 0; j < 32; j++) nf[j] = fmaf(h2[i], ow[kk * 32 + j], nf[j]);
            nt0 = fmaf(h2[i], cw[kk * 2 + 0], nt0);
            nt1 = fmaf(h2[i], cw[kk * 2 + 1], nt1);
        }
    }
    float4* o = reinterpret_cast<float4*>(out + (size_t)r * 32);
#pragma unroll
    for (int c = 0; c < 8; c++) {
        o[c] = make_float4(nf[c * 4 + 0], nf[c * 4 + 1], nf[c * 4 + 2], nf[c * 4 + 3]);
    }
    float2* o2 = reinterpret_cast<float2*>(out + (size_t)NN * 32);
    o2[r] = make_float2(nt0, nt1);
}

extern "C" void kernel_launch(void* const* d_in, const int* in_sizes, int n_in,
                              void* d_out, int out_size, void* d_ws, size_t ws_size,
                              hipStream_t stream) {
    const int N = NN, E = EE;
    const float* front_x = (const float*)d_in[0];
    const float* side_x = (const float*)d_in[1];
    const int* fei = (const int*)d_in[2];
    const int* sei = (const int*)d_in[3];
    const float* fe_enc_w1 = (const float*)d_in[4];
    const float* fe_enc_b1 = (const float*)d_in[5];
    const float* fe_enc_w2 = (const float*)d_in[6];
    const float* fe_enc_b2 = (const float*)d_in[7];
    const float* fe_conv_w = (const float*)d_in[8];
    const float* fe_conv_b = (const float*)d_in[9];
    const float* se_enc_w1 = (const float*)d_in[10];
    const float* se_enc_b1 = (const float*)d_in[11];
    const float* se_enc_w2 = (const float*)d_in[12];
    const float* se_enc_b2 = (const float*)d_in[13];
    const float* se_conv_w = (const float*)d_in[14];
    const float* se_conv_b = (const float*)d_in[15];
    const float* fus_w1 = (const float*)d_in[16];
    const float* fus_b1 = (const float*)d_in[17];
    const float* fus_w2 = (const float*)d_in[18];
    const float* fus_b2 = (const float*)d_in[19];
    const float* out_w = (const float*)d_in[20];
    const float* out_b = (const float*)d_in[21];
    const float* cls_w = (const float*)d_in[22];
    const float* cls_b = (const float*)d_in[23];

    // workspace carve (256B aligned)
    char* ws = (char*)d_ws;
    size_t off = 0;
    auto take = [&](size_t bytes) -> char* {
        char* p = ws + off;
        off = (off + bytes + 255) & ~(size_t)255;
        return p;
    };
    int* rp0 = (int*)take((size_t)(KN + 1) * 4);
    int* rp1 = (int*)take((size_t)(KN + 1) * 4);
    float* dv0 = (float*)take((size_t)N * 4);
    float* dv1 = (float*)take((size_t)N * 4);
    int* part0 = (int*)take(256 * 4);
    int* part1 = (int*)take(256 * 4);
    int2* ec0 = (int2*)take((size_t)E * 8);
    int2* ec1 = (int2*)take((size_t)E * 8);
    unsigned short* P0 = (unsigned short*)take((size_t)N * 64 * 2);
    unsigned short* P1 = (unsigned short*)take((size_t)N * 64 * 2);
    unsigned short* Q0 = (unsigned short*)take((size_t)N * 64 * 2);
    unsigned short* Q1 = (unsigned short*)take((size_t)N * 64 * 2);
    // cnt/pos alias onto P0/P1 (dead until conv layer 1 writes P)
    int* cnt0 = (int*)P0;
    int* cnt1 = cnt0 + KN;
    int* pos0 = (int*)P1;
    int* pos1 = pos0 + E;

    const int NB_ROW = (N + 255) / 256;
    const int NB_E = (E + 255) / 256;
    const int NB_C = N / 32;                  // exact: N % 32 == 0
    const int SBK = (KN + 8191) / 8192;       // 159 <= 256

    // ---- CSR build for both graphs (bucket-sorted rows) ----
    hipMemsetAsync(cnt0, 0, (size_t)2 * KN * 4, stream);
    k_count_dual<<<dim3(NB_E, 2), 256, 0, stream>>>(fei, sei, cnt0, cnt1, pos0, pos1, E);
    k_scan_partial_dual<<<dim3(SBK, 2), 256, 0, stream>>>(cnt0, cnt1, part0, part1, KN);
    k_scan_single_dual<<<dim3(1, 2), 256, 0, stream>>>(part0, part1, SBK);
    k_scan_write_dual<<<dim3(SBK, 2), 256, 0, stream>>>(cnt0, cnt1, part0, part1, rp0, rp1, KN, E);
    k_dinv_dual<<<dim3(NB_ROW, 2), 256, 0, stream>>>(rp0, rp1, dv0, dv1, N);
    k_fill_dual<<<dim3(NB_E, 2), 256, 0, stream>>>(fei, sei, pos0, pos1, dv0, dv1, rp0, rp1, ec0, ec1, E);

    // ---- encoders (dual, fused 2-layer MLP) ----
    k_enc_dual<<<dim3(NB_ROW, 2), 256, 0, stream>>>(front_x, side_x, fe_enc_w1, se_enc_w1,
                                                    fe_enc_b1, se_enc_b1, fe_enc_w2, se_enc_w2,
                                                    fe_enc_b2, se_enc_b2, Q0, Q1, N);
    // ---- 3 fused conv layers (dual):  Q->P->Q->P ----
    k_conv_dual<<<dim3(NB_C, 2), 256, 0, stream>>>(Q0, Q1, ec0, ec1, rp0, rp1, dv0, dv1,
                                                   fe_conv_w + 0 * 4096, se_conv_w + 0 * 4096,
                                                   fe_conv_b + 0 * 64, se_conv_b + 0 * 64, P0, P1);
    k_conv_dual<<<dim3(NB_C, 2), 256, 0, stream>>>(P0, P1, ec0, ec1, rp0, rp1, dv0, dv1,
                                                   fe_conv_w + 1 * 4096, se_conv_w + 1 * 4096,
                                                   fe_conv_b + 1 * 64, se_conv_b + 1 * 64, Q0, Q1);
    k_conv_dual<<<dim3(NB_C, 2), 256, 0, stream>>>(Q0, Q1, ec0, ec1, rp0, rp1, dv0, dv1,
                                                   fe_conv_w + 2 * 4096, se_conv_w + 2 * 4096,
                                                   fe_conv_b + 2 * 64, se_conv_b + 2 * 64, P0, P1);

    // ---- fused fusion-MLP + heads ----
    k_tail<<<NB_ROW, 256, 0, stream>>>(P0, P1, fus_w1, fus_b1, fus_w2, fus_b2,
                                       out_w, out_b, cls_w, cls_b, (float*)d_out, N);
}

// Round 7
// 782.784 us; speedup vs baseline: 1.2999x; 1.2999x over previous
//
#include <hip/hip_runtime.h>

#define DEV __device__ __forceinline__

static const int NN = 100000;
static const int EE = 1000000;

typedef unsigned int uv4 __attribute__((ext_vector_type(4)));
typedef int iv2 __attribute__((ext_vector_type(2)));

DEV float bf2f(unsigned int h) {
    unsigned int u = h << 16;
    float f;
    __builtin_memcpy(&f, &u, 4);
    return f;
}
DEV unsigned short f2bf(float f) {  // round-to-nearest-even
    unsigned int u;
    __builtin_memcpy(&u, &f, 4);
    u = u + 0x7FFFu + ((u >> 16) & 1u);
    return (unsigned short)(u >> 16);
}
DEV unsigned int pk2(float a, float b) {
    return (unsigned int)f2bf(a) | ((unsigned int)f2bf(b) << 16);
}
DEV void unpack8(uint4 u, float* v) {
    v[0] = bf2f(u.x & 0xffffu); v[1] = bf2f(u.x >> 16);
    v[2] = bf2f(u.y & 0xffffu); v[3] = bf2f(u.y >> 16);
    v[4] = bf2f(u.z & 0xffffu); v[5] = bf2f(u.z >> 16);
    v[6] = bf2f(u.w & 0xffffu); v[7] = bf2f(u.w >> 16);
}
DEV void store_row64(unsigned short* __restrict__ out, int r, const float* acc, bool relu) {
    uint4* o = reinterpret_cast<uint4*>(out + (size_t)r * 64);
#pragma unroll
    for (int c = 0; c < 8; c++) {
        float a[8];
#pragma unroll
        for (int i = 0; i < 8; i++) {
            float x = acc[c * 8 + i];
            a[i] = relu ? fmaxf(x, 0.0f) : x;
        }
        uint4 u;
        u.x = pk2(a[0], a[1]); u.y = pk2(a[2], a[3]);
        u.z = pk2(a[4], a[5]); u.w = pk2(a[6], a[7]);
        o[c] = u;
    }
}

// ---------------- CSR build (dual-graph via blockIdx.y) ----------------
// count + per-edge rank (pos) in one pass
__global__ __launch_bounds__(256) void k_count_dual(const int* __restrict__ d0, const int* __restrict__ d1,
                                                    int* __restrict__ c0, int* __restrict__ c1,
                                                    int* __restrict__ p0, int* __restrict__ p1, int e) {
    int g = blockIdx.y;
    const int* dst = g ? d1 : d0;
    int* cnt = g ? c1 : c0;
    int* pos = g ? p1 : p0;
    int i = blockIdx.x * blockDim.x + threadIdx.x;
    if (i < e) pos[i] = atomicAdd(&cnt[dst[i]], 1);
}
// block-sum partials + dinv (folded)
__global__ __launch_bounds__(256) void k_scan_partial_dual(const int* __restrict__ c0, const int* __restrict__ c1,
                                                           int* __restrict__ p0, int* __restrict__ p1,
                                                           float* __restrict__ v0, float* __restrict__ v1, int n) {
    int g = blockIdx.y;
    const int* cnt = g ? c1 : c0;
    int* partial = g ? p1 : p0;
    float* dinv = g ? v1 : v0;
    __shared__ int lds[256];
    int base = blockIdx.x * 1024;
    int t = threadIdx.x;
    int s = 0;
#pragma unroll
    for (int i = 0; i < 4; i++) {
        int idx = base + t * 4 + i;
        int c = (idx < n) ? cnt[idx] : 0;
        if (idx < n) dinv[idx] = rsqrtf((float)c + 1.0f);
        s += c;
    }
    lds[t] = s;
    __syncthreads();
    for (int off = 128; off > 0; off >>= 1) {
        if (t < off) lds[t] += lds[t + off];
        __syncthreads();
    }
    if (t == 0) partial[blockIdx.x] = lds[0];
}
__global__ __launch_bounds__(256) void k_scan_single_dual(int* __restrict__ p0, int* __restrict__ p1, int B) {
    int g = blockIdx.y;
    int* partial = g ? p1 : p0;
    __shared__ int lds[256];
    int t = threadIdx.x;
    int v = (t < B) ? partial[t] : 0;
    lds[t] = v;
    __syncthreads();
    for (int off = 1; off < 256; off <<= 1) {
        int x = (t >= off) ? lds[t - off] : 0;
        __syncthreads();
        lds[t] += x;
        __syncthreads();
    }
    if (t < B) partial[t] = lds[t] - v;  // exclusive
}
__global__ __launch_bounds__(256) void k_scan_write_dual(const int* __restrict__ c0, const int* __restrict__ c1,
                                                         const int* __restrict__ p0, const int* __restrict__ p1,
                                                         int* __restrict__ r0, int* __restrict__ r1,
                                                         int n, int total) {
    int g = blockIdx.y;
    const int* cnt = g ? c1 : c0;
    const int* partial = g ? p1 : p0;
    int* rowptr = g ? r1 : r0;
    __shared__ int lds[256];
    int base = blockIdx.x * 1024;
    int t = threadIdx.x;
    int v[4];
    int s = 0;
#pragma unroll
    for (int i = 0; i < 4; i++) {
        int idx = base + t * 4 + i;
        v[i] = (idx < n) ? cnt[idx] : 0;
        s += v[i];
    }
    lds[t] = s;
    __syncthreads();
    int mine = s;
    for (int off = 1; off < 256; off <<= 1) {
        int x = (t >= off) ? lds[t - off] : 0;
        __syncthreads();
        lds[t] += x;
        __syncthreads();
    }
    int run = lds[t] - mine + partial[blockIdx.x];
#pragma unroll
    for (int i = 0; i < 4; i++) {
        int idx = base + t * 4 + i;
        if (idx < n) rowptr[idx] = run;
        run += v[i];
    }
    if (blockIdx.x == 0 && t == 0) rowptr[n] = total;
}
// atomic-free fill using precomputed pos
__global__ __launch_bounds__(256) void k_fill_dual(const int* __restrict__ s0, const int* __restrict__ s1,
                                                   const int* __restrict__ q0, const int* __restrict__ q1,
                                                   const float* __restrict__ v0, const float* __restrict__ v1,
                                                   const int* __restrict__ r0, const int* __restrict__ r1,
                                                   iv2* __restrict__ e0, iv2* __restrict__ e1, int e) {
    int g = blockIdx.y;
    const int* src = g ? s1 : s0;
    const int* dstv = src + e;
    const int* pos = g ? q1 : q0;
    const float* dinv = g ? v1 : v0;
    const int* rowptr = g ? r1 : r0;
    iv2* ec = g ? e1 : e0;
    int i = blockIdx.x * blockDim.x + threadIdx.x;
    if (i >= e) return;
    int s = src[i], d = dstv[i];
    int idx = rowptr[d] + pos[i];
    iv2 rec;
    rec.x = s;
    rec.y = __float_as_int(dinv[s] * dinv[d]);
    __builtin_nontemporal_store(rec, ec + idx);
}

// ---------------- fused encoder MLP: relu(x@w1+b1)@w2+b2 -> bf16  (dual) ----------------
__global__ __launch_bounds__(256) void k_enc_dual(const float* __restrict__ x0, const float* __restrict__ x1,
                                                  const float* __restrict__ w1a, const float* __restrict__ w1b,
                                                  const float* __restrict__ b1a, const float* __restrict__ b1b,
                                                  const float* __restrict__ w2a, const float* __restrict__ w2b,
                                                  const float* __restrict__ b2a, const float* __restrict__ b2b,
                                                  unsigned short* __restrict__ y0, unsigned short* __restrict__ y1,
                                                  int n) {
    int g = blockIdx.y;
    const float* x = g ? x1 : x0;
    const float* w1 = g ? w1b : w1a;
    const float* b1 = g ? b1b : b1a;
    const float* w2 = g ? w2b : w2a;
    const float* b2 = g ? b2b : b2a;
    unsigned short* out = g ? y1 : y0;
    int r = blockIdx.x * blockDim.x + threadIdx.x;
    if (r >= n) return;
    float4 xv = reinterpret_cast<const float4*>(x)[r];
    float xk[4] = {xv.x, xv.y, xv.z, xv.w};
    float h2[64];
#pragma unroll
    for (int j = 0; j < 64; j++) h2[j] = b2[j];
#pragma unroll
    for (int c = 0; c < 8; c++) {  // h1 in chunks of 8
        float h[8];
#pragma unroll
        for (int i = 0; i < 8; i++) h[i] = b1[c * 8 + i];
#pragma unroll
        for (int k = 0; k < 4; k++) {
#pragma unroll
            for (int i = 0; i < 8; i++) h[i] = fmaf(xk[k], w1[k * 64 + c * 8 + i], h[i]);
        }
#pragma unroll
        for (int i = 0; i < 8; i++) h[i] = fmaxf(h[i], 0.0f);
#pragma unroll
        for (int i = 0; i < 8; i++) {
            const float* wr = w2 + (c * 8 + i) * 64;
#pragma unroll
            for (int j = 0; j < 64; j++) h2[j] = fmaf(h[i], wr[j], h2[j]);
        }
    }
    store_row64(out, r, h2, false);
}

// ---------------- fused GCN layer: y = relu( (A_hat x) W + b ) ----------------
// XCD-partitioned dual: blocks dispatch round-robin to XCDs; xcd 0-3 -> graph 0,
// xcd 4-7 -> graph 1, so each XCD's L2 caches rows of only one graph's x.
DEV void fma_edge(float* acc, uint4 u, float c) {
    float v[8];
    unpack8(u, v);
#pragma unroll
    for (int i = 0; i < 8; i++) acc[i] = fmaf(v[i], c, acc[i]);
}
__global__ __launch_bounds__(256) void k_conv_dual(const unsigned short* __restrict__ x0,
                                                   const unsigned short* __restrict__ x1,
                                                   const int2* __restrict__ ec0, const int2* __restrict__ ec1,
                                                   const int* __restrict__ r0, const int* __restrict__ r1,
                                                   const float* __restrict__ v0, const float* __restrict__ v1,
                                                   const float* __restrict__ w0, const float* __restrict__ w1,
                                                   const float* __restrict__ b0, const float* __restrict__ b1,
                                                   unsigned short* __restrict__ y0, unsigned short* __restrict__ y1,
                                                   int nblk) {
    int bx = blockIdx.x;
    int xcd = bx & 7;
    int g = xcd >> 2;                    // 0..3 -> graph0, 4..7 -> graph1
    int lin = (bx >> 3) * 4 + (xcd & 3); // per-graph block index
    if (lin >= nblk) return;             // block-uniform exit (barriers safe)
    const unsigned short* x = g ? x1 : x0;
    const int2* ec = g ? ec1 : ec0;
    const int* rowptr = g ? r1 : r0;
    const float* dinv = g ? v1 : v0;
    const float* w = g ? w1 : w0;
    const float* b = g ? b1 : b0;
    unsigned short* y = g ? y1 : y0;

    __shared__ float agg[32][68];  // pad 64->68: phase-2 reads conflict-free

    int t = threadIdx.x;
    int cl = t >> 3;   // local node 0..31
    int ln = t & 7;    // feature-octet lane
    int node = lin * 32 + cl;
    int fbase = ln * 8;
    float acc[8];
    {
        float d = dinv[node];
        float d2 = d * d;
        uint4 su = *reinterpret_cast<const uint4*>(x + (size_t)node * 64 + fbase);
        float sv[8];
        unpack8(su, sv);
#pragma unroll
        for (int i = 0; i < 8; i++) acc[i] = sv[i] * d2;
    }
    int e = rowptr[node], e1 = rowptr[node + 1];
    // 4-wide: independent gathers in flight
    for (; e + 4 <= e1; e += 4) {
        const long long* ep = reinterpret_cast<const long long*>(ec + e);
        long long p0 = __builtin_nontemporal_load(ep + 0);
        long long p1 = __builtin_nontemporal_load(ep + 1);
        long long p2 = __builtin_nontemporal_load(ep + 2);
        long long p3 = __builtin_nontemporal_load(ep + 3);
        int s0 = (int)p0, s1 = (int)p1, s2 = (int)p2, s3 = (int)p3;
        uint4 u0 = *reinterpret_cast<const uint4*>(x + (size_t)s0 * 64 + fbase);
        uint4 u1 = *reinterpret_cast<const uint4*>(x + (size_t)s1 * 64 + fbase);
        uint4 u2 = *reinterpret_cast<const uint4*>(x + (size_t)s2 * 64 + fbase);
        uint4 u3 = *reinterpret_cast<const uint4*>(x + (size_t)s3 * 64 + fbase);
        fma_edge(acc, u0, __int_as_float((int)(p0 >> 32)));
        fma_edge(acc, u1, __int_as_float((int)(p1 >> 32)));
        fma_edge(acc, u2, __int_as_float((int)(p2 >> 32)));
        fma_edge(acc, u3, __int_as_float((int)(p3 >> 32)));
    }
    if (e + 2 <= e1) {
        const long long* ep = reinterpret_cast<const long long*>(ec + e);
        long long p0 = __builtin_nontemporal_load(ep + 0);
        long long p1 = __builtin_nontemporal_load(ep + 1);
        int s0 = (int)p0, s1 = (int)p1;
        uint4 u0 = *reinterpret_cast<const uint4*>(x + (size_t)s0 * 64 + fbase);
        uint4 u1 = *reinterpret_cast<const uint4*>(x + (size_t)s1 * 64 + fbase);
        fma_edge(acc, u0, __int_as_float((int)(p0 >> 32)));
        fma_edge(acc, u1, __int_as_float((int)(p1 >> 32)));
        e += 2;
    }
    if (e < e1) {
        long long p0 = __builtin_nontemporal_load(reinterpret_cast<const long long*>(ec + e));
        int s0 = (int)p0;
        uint4 u0 = *reinterpret_cast<const uint4*>(x + (size_t)s0 * 64 + fbase);
        fma_edge(acc, u0, __int_as_float((int)(p0 >> 32)));
    }
#pragma unroll
    for (int i = 0; i < 8; i += 4) {
        *reinterpret_cast<float4*>(&agg[cl][fbase + i]) = make_float4(acc[i], acc[i + 1], acc[i + 2], acc[i + 3]);
    }
    __syncthreads();

    // phase 2: out[fbase..fbase+8) = b + sum_k agg[cl][k] * W[k][fbase..]
    float out[8];
#pragma unroll
    for (int i = 0; i < 8; i++) out[i] = b[fbase + i];
#pragma unroll 4
    for (int k4 = 0; k4 < 16; k4++) {
        float4 av = *reinterpret_cast<const float4*>(&agg[cl][k4 * 4]);
        float a[4] = {av.x, av.y, av.z, av.w};
#pragma unroll
        for (int kk = 0; kk < 4; kk++) {
            const float4* wr = reinterpret_cast<const float4*>(w + (k4 * 4 + kk) * 64 + fbase);
            float4 wv0 = wr[0], wv1 = wr[1];
            out[0] = fmaf(a[kk], wv0.x, out[0]);
            out[1] = fmaf(a[kk], wv0.y, out[1]);
            out[2] = fmaf(a[kk], wv0.z, out[2]);
            out[3] = fmaf(a[kk], wv0.w, out[3]);
            out[4] = fmaf(a[kk], wv1.x, out[4]);
            out[5] = fmaf(a[kk], wv1.y, out[5]);
            out[6] = fmaf(a[kk], wv1.z, out[6]);
            out[7] = fmaf(a[kk], wv1.w, out[7]);
        }
    }
    uint4 ou;
    float r[8];
#pragma unroll
    for (int i = 0; i < 8; i++) r[i] = fmaxf(out[i], 0.0f);
    ou.x = pk2(r[0], r[1]); ou.y = pk2(r[2], r[3]); ou.z = pk2(r[4], r[5]); ou.w = pk2(r[6], r[7]);
    // NORMAL store: y is next layer's gather-hot x — keep it cache-resident.
    *reinterpret_cast<uint4*>(y + (size_t)node * 64 + fbase) = ou;
}

// ---------------- fused tail: concat-MLP + both heads ----------------
__global__ __launch_bounds__(256) void k_tail(const unsigned short* __restrict__ F,
                                              const unsigned short* __restrict__ S,
                                              const float* __restrict__ w1, const float* __restrict__ b1,
                                              const float* __restrict__ w2, const float* __restrict__ b2,
                                              const float* __restrict__ ow, const float* __restrict__ ob,
                                              const float* __restrict__ cw, const float* __restrict__ cb,
                                              float* __restrict__ out, int n) {
    int r = blockIdx.x * blockDim.x + threadIdx.x;
    if (r >= n) return;
    float h1[64];
#pragma unroll
    for (int j = 0; j < 64; j++) h1[j] = b1[j];
    const uint4* Fr = reinterpret_cast<const uint4*>(F + (size_t)r * 64);
    const uint4* Sr = reinterpret_cast<const uint4*>(S + (size_t)r * 64);
#pragma unroll 1
    for (int k0 = 0; k0 < 8; k0++) {
        uint4 u = Fr[k0];
        float v[8];
        unpack8(u, v);
        const float* wk = w1 + k0 * 8 * 64;
#pragma unroll
        for (int i = 0; i < 8; i++) {
#pragma unroll
            for (int j = 0; j < 64; j++) h1[j] = fmaf(v[i], wk[i * 64 + j], h1[j]);
        }
    }
#pragma unroll 1
    for (int k0 = 0; k0 < 8; k0++) {
        uint4 u = Sr[k0];
        float v[8];
        unpack8(u, v);
        const float* wk = w1 + (64 + k0 * 8) * 64;
#pragma unroll
        for (int i = 0; i < 8; i++) {
#pragma unroll
            for (int j = 0; j < 64; j++) h1[j] = fmaf(v[i], wk[i * 64 + j], h1[j]);
        }
    }
#pragma unroll
    for (int j = 0; j < 64; j++) h1[j] = fmaxf(h1[j], 0.0f);

    float nf[32];
#pragma unroll
    for (int j = 0; j < 32; j++) nf[j] = ob[j];
    float nt0 = cb[0], nt1 = cb[1];
#pragma unroll 1
    for (int c = 0; c < 8; c++) {  // h2 in chunks of 8
        float h2[8];
#pragma unroll
        for (int i = 0; i < 8; i++) h2[i] = b2[c * 8 + i];
#pragma unroll
        for (int k = 0; k < 64; k++) {
            const float* wr = w2 + k * 64 + c * 8;
#pragma unroll
            for (int i = 0; i < 8; i++) h2[i] = fmaf(h1[k], wr[i], h2[i]);
        }
#pragma unroll
        for (int i = 0; i < 8; i++) {
            int kk = c * 8 + i;
#pragma unroll
            for (int j = 0; j < 32; j++) nf[j] = fmaf(h2[i], ow[kk * 32 + j], nf[j]);
            nt0 = fmaf(h2[i], cw[kk * 2 + 0], nt0);
            nt1 = fmaf(h2[i], cw[kk * 2 + 1], nt1);
        }
    }
    float4* o = reinterpret_cast<float4*>(out + (size_t)r * 32);
#pragma unroll
    for (int c = 0; c < 8; c++) {
        o[c] = make_float4(nf[c * 4 + 0], nf[c * 4 + 1], nf[c * 4 + 2], nf[c * 4 + 3]);
    }
    float2* o2 = reinterpret_cast<float2*>(out + (size_t)NN * 32);
    o2[r] = make_float2(nt0, nt1);
}

extern "C" void kernel_launch(void* const* d_in, const int* in_sizes, int n_in,
                              void* d_out, int out_size, void* d_ws, size_t ws_size,
                              hipStream_t stream) {
    const int N = NN, E = EE;
    const float* front_x = (const float*)d_in[0];
    const float* side_x = (const float*)d_in[1];
    const int* fei = (const int*)d_in[2];
    const int* sei = (const int*)d_in[3];
    const float* fe_enc_w1 = (const float*)d_in[4];
    const float* fe_enc_b1 = (const float*)d_in[5];
    const float* fe_enc_w2 = (const float*)d_in[6];
    const float* fe_enc_b2 = (const float*)d_in[7];
    const float* fe_conv_w = (const float*)d_in[8];
    const float* fe_conv_b = (const float*)d_in[9];
    const float* se_enc_w1 = (const float*)d_in[10];
    const float* se_enc_b1 = (const float*)d_in[11];
    const float* se_enc_w2 = (const float*)d_in[12];
    const float* se_enc_b2 = (const float*)d_in[13];
    const float* se_conv_w = (const float*)d_in[14];
    const float* se_conv_b = (const float*)d_in[15];
    const float* fus_w1 = (const float*)d_in[16];
    const float* fus_b1 = (const float*)d_in[17];
    const float* fus_w2 = (const float*)d_in[18];
    const float* fus_b2 = (const float*)d_in[19];
    const float* out_w = (const float*)d_in[20];
    const float* out_b = (const float*)d_in[21];
    const float* cls_w = (const float*)d_in[22];
    const float* cls_b = (const float*)d_in[23];

    // workspace carve (256B aligned)
    char* ws = (char*)d_ws;
    size_t off = 0;
    auto take = [&](size_t bytes) -> char* {
        char* p = ws + off;
        off = (off + bytes + 255) & ~(size_t)255;
        return p;
    };
    int* zb = (int*)take((size_t)2 * N * 4);  // cnt0,cnt1 (zeroed)
    int* cnt0 = zb;
    int* cnt1 = zb + N;
    int* pos0 = (int*)take((size_t)E * 4);
    int* pos1 = (int*)take((size_t)E * 4);
    int* rp0 = (int*)take((size_t)(N + 1) * 4);
    int* rp1 = (int*)take((size_t)(N + 1) * 4);
    float* dv0 = (float*)take((size_t)N * 4);
    float* dv1 = (float*)take((size_t)N * 4);
    int* part0 = (int*)take(256 * 4);
    int* part1 = (int*)take(256 * 4);
    int2* ec0 = (int2*)take((size_t)E * 8);
    int2* ec1 = (int2*)take((size_t)E * 8);
    unsigned short* P0 = (unsigned short*)take((size_t)N * 64 * 2);
    unsigned short* P1 = (unsigned short*)take((size_t)N * 64 * 2);
    unsigned short* Q0 = (unsigned short*)take((size_t)N * 64 * 2);
    unsigned short* Q1 = (unsigned short*)take((size_t)N * 64 * 2);

    const int NB_ROW = (N + 255) / 256;
    const int NB_E = (E + 255) / 256;
    const int NB_C = N / 32;                       // 3125 blocks per graph
    const int GX_C = ((2 * NB_C + 7) / 8) * 8;     // XCD-aligned grid for conv
    const int SB = (N + 1023) / 1024;

    // ---- CSR build for both graphs ----
    hipMemsetAsync(zb, 0, (size_t)2 * N * 4, stream);
    k_count_dual<<<dim3(NB_E, 2), 256, 0, stream>>>(fei + E, sei + E, cnt0, cnt1, pos0, pos1, E);
    k_scan_partial_dual<<<dim3(SB, 2), 256, 0, stream>>>(cnt0, cnt1, part0, part1, dv0, dv1, N);
    k_scan_single_dual<<<dim3(1, 2), 256, 0, stream>>>(part0, part1, SB);
    k_scan_write_dual<<<dim3(SB, 2), 256, 0, stream>>>(cnt0, cnt1, part0, part1, rp0, rp1, N, E);
    k_fill_dual<<<dim3(NB_E, 2), 256, 0, stream>>>(fei, sei, pos0, pos1, dv0, dv1, rp0, rp1,
                                                   (iv2*)ec0, (iv2*)ec1, E);

    // ---- encoders (dual, fused 2-layer MLP) ----
    k_enc_dual<<<dim3(NB_ROW, 2), 256, 0, stream>>>(front_x, side_x, fe_enc_w1, se_enc_w1,
                                                    fe_enc_b1, se_enc_b1, fe_enc_w2, se_enc_w2,
                                                    fe_enc_b2, se_enc_b2, Q0, Q1, N);
    // ---- 3 fused conv layers (XCD-partitioned dual):  Q->P->Q->P ----
    k_conv_dual<<<GX_C, 256, 0, stream>>>(Q0, Q1, ec0, ec1, rp0, rp1, dv0, dv1,
                                          fe_conv_w + 0 * 4096, se_conv_w + 0 * 4096,
                                          fe_conv_b + 0 * 64, se_conv_b + 0 * 64, P0, P1, NB_C);
    k_conv_dual<<<GX_C, 256, 0, stream>>>(P0, P1, ec0, ec1, rp0, rp1, dv0, dv1,
                                          fe_conv_w + 1 * 4096, se_conv_w + 1 * 4096,
                                          fe_conv_b + 1 * 64, se_conv_b + 1 * 64, Q0, Q1, NB_C);
    k_conv_dual<<<GX_C, 256, 0, stream>>>(Q0, Q1, ec0, ec1, rp0, rp1, dv0, dv1,
                                          fe_conv_w + 2 * 4096, se_conv_w + 2 * 4096,
                                          fe_conv_b + 2 * 64, se_conv_b + 2 * 64, P0, P1, NB_C);

    // ---- fused fusion-MLP + heads ----
    k_tail<<<NB_ROW, 256, 0, stream>>>(P0, P1, fus_w1, fus_b1, fus_w2, fus_b2,
                                       out_w, out_b, cls_w, cls_b, (float*)d_out, N);
}

// Round 8
// 741.116 us; speedup vs baseline: 1.3730x; 1.0562x over previous
//
#include <hip/hip_runtime.h>

#define DEV __device__ __forceinline__

static const int NN = 100000;
static const int EE = 1000000;
static const int ECAP = 1024;   // LDS-staged edges per block (32 nodes, avg ~320)

typedef unsigned int uv4 __attribute__((ext_vector_type(4)));
typedef int iv2 __attribute__((ext_vector_type(2)));

DEV float bf2f(unsigned int h) {
    unsigned int u = h << 16;
    float f;
    __builtin_memcpy(&f, &u, 4);
    return f;
}
DEV unsigned short f2bf(float f) {  // round-to-nearest-even
    unsigned int u;
    __builtin_memcpy(&u, &f, 4);
    u = u + 0x7FFFu + ((u >> 16) & 1u);
    return (unsigned short)(u >> 16);
}
DEV unsigned int pk2(float a, float b) {
    return (unsigned int)f2bf(a) | ((unsigned int)f2bf(b) << 16);
}
DEV void unpack8(uint4 u, float* v) {
    v[0] = bf2f(u.x & 0xffffu); v[1] = bf2f(u.x >> 16);
    v[2] = bf2f(u.y & 0xffffu); v[3] = bf2f(u.y >> 16);
    v[4] = bf2f(u.z & 0xffffu); v[5] = bf2f(u.z >> 16);
    v[6] = bf2f(u.w & 0xffffu); v[7] = bf2f(u.w >> 16);
}
DEV void store_row64(unsigned short* __restrict__ out, int r, const float* acc, bool relu) {
    uint4* o = reinterpret_cast<uint4*>(out + (size_t)r * 64);
#pragma unroll
    for (int c = 0; c < 8; c++) {
        float a[8];
#pragma unroll
        for (int i = 0; i < 8; i++) {
            float x = acc[c * 8 + i];
            a[i] = relu ? fmaxf(x, 0.0f) : x;
        }
        uint4 u;
        u.x = pk2(a[0], a[1]); u.y = pk2(a[2], a[3]);
        u.z = pk2(a[4], a[5]); u.w = pk2(a[6], a[7]);
        o[c] = u;
    }
}

// ---------------- CSR build (dual-graph via blockIdx.y) ----------------
__global__ __launch_bounds__(256) void k_count_dual(const int* __restrict__ d0, const int* __restrict__ d1,
                                                    int* __restrict__ c0, int* __restrict__ c1,
                                                    int* __restrict__ p0, int* __restrict__ p1, int e) {
    int g = blockIdx.y;
    const int* dst = g ? d1 : d0;
    int* cnt = g ? c1 : c0;
    int* pos = g ? p1 : p0;
    int i = blockIdx.x * blockDim.x + threadIdx.x;
    if (i < e) pos[i] = atomicAdd(&cnt[dst[i]], 1);
}
__global__ __launch_bounds__(256) void k_scan_partial_dual(const int* __restrict__ c0, const int* __restrict__ c1,
                                                           int* __restrict__ p0, int* __restrict__ p1,
                                                           float* __restrict__ v0, float* __restrict__ v1, int n) {
    int g = blockIdx.y;
    const int* cnt = g ? c1 : c0;
    int* partial = g ? p1 : p0;
    float* dinv = g ? v1 : v0;
    __shared__ int lds[256];
    int base = blockIdx.x * 1024;
    int t = threadIdx.x;
    int s = 0;
#pragma unroll
    for (int i = 0; i < 4; i++) {
        int idx = base + t * 4 + i;
        int c = (idx < n) ? cnt[idx] : 0;
        if (idx < n) dinv[idx] = rsqrtf((float)c + 1.0f);
        s += c;
    }
    lds[t] = s;
    __syncthreads();
    for (int off = 128; off > 0; off >>= 1) {
        if (t < off) lds[t] += lds[t + off];
        __syncthreads();
    }
    if (t == 0) partial[blockIdx.x] = lds[0];
}
__global__ __launch_bounds__(256) void k_scan_single_dual(int* __restrict__ p0, int* __restrict__ p1, int B) {
    int g = blockIdx.y;
    int* partial = g ? p1 : p0;
    __shared__ int lds[256];
    int t = threadIdx.x;
    int v = (t < B) ? partial[t] : 0;
    lds[t] = v;
    __syncthreads();
    for (int off = 1; off < 256; off <<= 1) {
        int x = (t >= off) ? lds[t - off] : 0;
        __syncthreads();
        lds[t] += x;
        __syncthreads();
    }
    if (t < B) partial[t] = lds[t] - v;  // exclusive
}
__global__ __launch_bounds__(256) void k_scan_write_dual(const int* __restrict__ c0, const int* __restrict__ c1,
                                                         const int* __restrict__ p0, const int* __restrict__ p1,
                                                         int* __restrict__ r0, int* __restrict__ r1,
                                                         int n, int total) {
    int g = blockIdx.y;
    const int* cnt = g ? c1 : c0;
    const int* partial = g ? p1 : p0;
    int* rowptr = g ? r1 : r0;
    __shared__ int lds[256];
    int base = blockIdx.x * 1024;
    int t = threadIdx.x;
    int v[4];
    int s = 0;
#pragma unroll
    for (int i = 0; i < 4; i++) {
        int idx = base + t * 4 + i;
        v[i] = (idx < n) ? cnt[idx] : 0;
        s += v[i];
    }
    lds[t] = s;
    __syncthreads();
    int mine = s;
    for (int off = 1; off < 256; off <<= 1) {
        int x = (t >= off) ? lds[t - off] : 0;
        __syncthreads();
        lds[t] += x;
        __syncthreads();
    }
    int run = lds[t] - mine + partial[blockIdx.x];
#pragma unroll
    for (int i = 0; i < 4; i++) {
        int idx = base + t * 4 + i;
        if (idx < n) rowptr[idx] = run;
        run += v[i];
    }
    if (blockIdx.x == 0 && t == 0) rowptr[n] = total;
}
__global__ __launch_bounds__(256) void k_fill_dual(const int* __restrict__ s0, const int* __restrict__ s1,
                                                   const int* __restrict__ q0, const int* __restrict__ q1,
                                                   const float* __restrict__ v0, const float* __restrict__ v1,
                                                   const int* __restrict__ r0, const int* __restrict__ r1,
                                                   iv2* __restrict__ e0, iv2* __restrict__ e1, int e) {
    int g = blockIdx.y;
    const int* src = g ? s1 : s0;
    const int* dstv = src + e;
    const int* pos = g ? q1 : q0;
    const float* dinv = g ? v1 : v0;
    const int* rowptr = g ? r1 : r0;
    iv2* ec = g ? e1 : e0;
    int i = blockIdx.x * blockDim.x + threadIdx.x;
    if (i >= e) return;
    int s = src[i], d = dstv[i];
    int idx = rowptr[d] + pos[i];
    iv2 rec;
    rec.x = s;
    rec.y = __float_as_int(dinv[s] * dinv[d]);
    __builtin_nontemporal_store(rec, ec + idx);
}

// ---------------- fused encoder MLP: relu(x@w1+b1)@w2+b2 -> bf16  (dual) ----------------
__global__ __launch_bounds__(256) void k_enc_dual(const float* __restrict__ x0, const float* __restrict__ x1,
                                                  const float* __restrict__ w1a, const float* __restrict__ w1b,
                                                  const float* __restrict__ b1a, const float* __restrict__ b1b,
                                                  const float* __restrict__ w2a, const float* __restrict__ w2b,
                                                  const float* __restrict__ b2a, const float* __restrict__ b2b,
                                                  unsigned short* __restrict__ y0, unsigned short* __restrict__ y1,
                                                  int n) {
    int g = blockIdx.y;
    const float* x = g ? x1 : x0;
    const float* w1 = g ? w1b : w1a;
    const float* b1 = g ? b1b : b1a;
    const float* w2 = g ? w2b : w2a;
    const float* b2 = g ? b2b : b2a;
    unsigned short* out = g ? y1 : y0;
    int r = blockIdx.x * blockDim.x + threadIdx.x;
    if (r >= n) return;
    float4 xv = reinterpret_cast<const float4*>(x)[r];
    float xk[4] = {xv.x, xv.y, xv.z, xv.w};
    float h2[64];
#pragma unroll
    for (int j = 0; j < 64; j++) h2[j] = b2[j];
#pragma unroll
    for (int c = 0; c < 8; c++) {  // h1 in chunks of 8
        float h[8];
#pragma unroll
        for (int i = 0; i < 8; i++) h[i] = b1[c * 8 + i];
#pragma unroll
        for (int k = 0; k < 4; k++) {
#pragma unroll
            for (int i = 0; i < 8; i++) h[i] = fmaf(xk[k], w1[k * 64 + c * 8 + i], h[i]);
        }
#pragma unroll
        for (int i = 0; i < 8; i++) h[i] = fmaxf(h[i], 0.0f);
#pragma unroll
        for (int i = 0; i < 8; i++) {
            const float* wr = w2 + (c * 8 + i) * 64;
#pragma unroll
            for (int j = 0; j < 64; j++) h2[j] = fmaf(h[i], wr[j], h2[j]);
        }
    }
    store_row64(out, r, h2, false);
}

// ---------------- fused GCN layer: y = relu( (A_hat x) W + b ) ----------------
// LDS-staged edge records: block's contiguous ec range is cooperatively loaded
// into LDS first, so the gather loop's chain is ds_read -> x gather (one global
// latency per epoch instead of two).
DEV void fma_edge(float* acc, uint4 u, float c) {
    float v[8];
    unpack8(u, v);
#pragma unroll
    for (int i = 0; i < 8; i++) acc[i] = fmaf(v[i], c, acc[i]);
}
__global__ __launch_bounds__(256) void k_conv_dual(const unsigned short* __restrict__ x0,
                                                   const unsigned short* __restrict__ x1,
                                                   const long long* __restrict__ ec0, const long long* __restrict__ ec1,
                                                   const int* __restrict__ r0, const int* __restrict__ r1,
                                                   const float* __restrict__ v0, const float* __restrict__ v1,
                                                   const float* __restrict__ w0, const float* __restrict__ w1,
                                                   const float* __restrict__ b0, const float* __restrict__ b1,
                                                   unsigned short* __restrict__ y0, unsigned short* __restrict__ y1,
                                                   int nblk) {
    int bx = blockIdx.x;
    int xcd = bx & 7;
    int g = xcd >> 2;                    // 0..3 -> graph0, 4..7 -> graph1
    int lin = (bx >> 3) * 4 + (xcd & 3); // per-graph block index
    if (lin >= nblk) return;             // block-uniform exit (barriers safe)
    const unsigned short* x = g ? x1 : x0;
    const long long* ec = g ? ec1 : ec0;
    const int* rowptr = g ? r1 : r0;
    const float* dinv = g ? v1 : v0;
    const float* w = g ? w1 : w0;
    const float* b = g ? b1 : b0;
    unsigned short* y = g ? y1 : y0;

    __shared__ long long eds[ECAP];  // 8 KB staged edge records
    __shared__ float agg[32][68];    // pad 64->68: phase-2 reads conflict-free

    int t = threadIdx.x;
    int cl = t >> 3;   // local node 0..31
    int ln = t & 7;    // feature-octet lane
    int node = lin * 32 + cl;
    int fbase = ln * 8;

    int nbase = lin * 32;
    int ebase = rowptr[nbase];
    int L = rowptr[nbase + 32] - ebase;
    int Ls = (L < ECAP) ? L : ECAP;
    for (int i = t; i < Ls; i += 256) {
        eds[i] = __builtin_nontemporal_load(ec + ebase + i);
    }

    float acc[8];
    {
        float d = dinv[node];
        float d2 = d * d;
        uint4 su = *reinterpret_cast<const uint4*>(x + (size_t)node * 64 + fbase);
        float sv[8];
        unpack8(su, sv);
#pragma unroll
        for (int i = 0; i < 8; i++) acc[i] = sv[i] * d2;
    }
    int e = rowptr[node] - ebase, e1 = rowptr[node + 1] - ebase;
    __syncthreads();

    if (e1 <= ECAP) {
        // LDS path (virtually always): 4 independent gathers per epoch
        for (; e + 4 <= e1; e += 4) {
            long long p0 = eds[e + 0];
            long long p1 = eds[e + 1];
            long long p2 = eds[e + 2];
            long long p3 = eds[e + 3];
            uint4 u0 = *reinterpret_cast<const uint4*>(x + (size_t)(int)p0 * 64 + fbase);
            uint4 u1 = *reinterpret_cast<const uint4*>(x + (size_t)(int)p1 * 64 + fbase);
            uint4 u2 = *reinterpret_cast<const uint4*>(x + (size_t)(int)p2 * 64 + fbase);
            uint4 u3 = *reinterpret_cast<const uint4*>(x + (size_t)(int)p3 * 64 + fbase);
            fma_edge(acc, u0, __int_as_float((int)(p0 >> 32)));
            fma_edge(acc, u1, __int_as_float((int)(p1 >> 32)));
            fma_edge(acc, u2, __int_as_float((int)(p2 >> 32)));
            fma_edge(acc, u3, __int_as_float((int)(p3 >> 32)));
        }
        if (e + 2 <= e1) {
            long long p0 = eds[e + 0];
            long long p1 = eds[e + 1];
            uint4 u0 = *reinterpret_cast<const uint4*>(x + (size_t)(int)p0 * 64 + fbase);
            uint4 u1 = *reinterpret_cast<const uint4*>(x + (size_t)(int)p1 * 64 + fbase);
            fma_edge(acc, u0, __int_as_float((int)(p0 >> 32)));
            fma_edge(acc, u1, __int_as_float((int)(p1 >> 32)));
            e += 2;
        }
        if (e < e1) {
            long long p0 = eds[e];
            uint4 u0 = *reinterpret_cast<const uint4*>(x + (size_t)(int)p0 * 64 + fbase);
            fma_edge(acc, u0, __int_as_float((int)(p0 >> 32)));
        }
    } else {
        // overflow fallback: read edge records from global
        for (; e < e1; e++) {
            long long p0 = __builtin_nontemporal_load(ec + ebase + e);
            uint4 u0 = *reinterpret_cast<const uint4*>(x + (size_t)(int)p0 * 64 + fbase);
            fma_edge(acc, u0, __int_as_float((int)(p0 >> 32)));
        }
    }
#pragma unroll
    for (int i = 0; i < 8; i += 4) {
        *reinterpret_cast<float4*>(&agg[cl][fbase + i]) = make_float4(acc[i], acc[i + 1], acc[i + 2], acc[i + 3]);
    }
    __syncthreads();

    // phase 2: out[fbase..fbase+8) = b + sum_k agg[cl][k] * W[k][fbase..]
    float out[8];
#pragma unroll
    for (int i = 0; i < 8; i++) out[i] = b[fbase + i];
#pragma unroll 4
    for (int k4 = 0; k4 < 16; k4++) {
        float4 av = *reinterpret_cast<const float4*>(&agg[cl][k4 * 4]);
        float a[4] = {av.x, av.y, av.z, av.w};
#pragma unroll
        for (int kk = 0; kk < 4; kk++) {
            const float4* wr = reinterpret_cast<const float4*>(w + (k4 * 4 + kk) * 64 + fbase);
            float4 wv0 = wr[0], wv1 = wr[1];
            out[0] = fmaf(a[kk], wv0.x, out[0]);
            out[1] = fmaf(a[kk], wv0.y, out[1]);
            out[2] = fmaf(a[kk], wv0.z, out[2]);
            out[3] = fmaf(a[kk], wv0.w, out[3]);
            out[4] = fmaf(a[kk], wv1.x, out[4]);
            out[5] = fmaf(a[kk], wv1.y, out[5]);
            out[6] = fmaf(a[kk], wv1.z, out[6]);
            out[7] = fmaf(a[kk], wv1.w, out[7]);
        }
    }
    uint4 ou;
    float r[8];
#pragma unroll
    for (int i = 0; i < 8; i++) r[i] = fmaxf(out[i], 0.0f);
    ou.x = pk2(r[0], r[1]); ou.y = pk2(r[2], r[3]); ou.z = pk2(r[4], r[5]); ou.w = pk2(r[6], r[7]);
    *reinterpret_cast<uint4*>(y + (size_t)node * 64 + fbase) = ou;
}

// ---------------- fused tail: concat-MLP + both heads ----------------
__global__ __launch_bounds__(256) void k_tail(const unsigned short* __restrict__ F,
                                              const unsigned short* __restrict__ S,
                                              const float* __restrict__ w1, const float* __restrict__ b1,
                                              const float* __restrict__ w2, const float* __restrict__ b2,
                                              const float* __restrict__ ow, const float* __restrict__ ob,
                                              const float* __restrict__ cw, const float* __restrict__ cb,
                                              float* __restrict__ out, int n) {
    int r = blockIdx.x * blockDim.x + threadIdx.x;
    if (r >= n) return;
    float h1[64];
#pragma unroll
    for (int j = 0; j < 64; j++) h1[j] = b1[j];
    const uint4* Fr = reinterpret_cast<const uint4*>(F + (size_t)r * 64);
    const uint4* Sr = reinterpret_cast<const uint4*>(S + (size_t)r * 64);
#pragma unroll 1
    for (int k0 = 0; k0 < 8; k0++) {
        uint4 u = Fr[k0];
        float v[8];
        unpack8(u, v);
        const float* wk = w1 + k0 * 8 * 64;
#pragma unroll
        for (int i = 0; i < 8; i++) {
#pragma unroll
            for (int j = 0; j < 64; j++) h1[j] = fmaf(v[i], wk[i * 64 + j], h1[j]);
        }
    }
#pragma unroll 1
    for (int k0 = 0; k0 < 8; k0++) {
        uint4 u = Sr[k0];
        float v[8];
        unpack8(u, v);
        const float* wk = w1 + (64 + k0 * 8) * 64;
#pragma unroll
        for (int i = 0; i < 8; i++) {
#pragma unroll
            for (int j = 0; j < 64; j++) h1[j] = fmaf(v[i], wk[i * 64 + j], h1[j]);
        }
    }
#pragma unroll
    for (int j = 0; j < 64; j++) h1[j] = fmaxf(h1[j], 0.0f);

    float nf[32];
#pragma unroll
    for (int j = 0; j < 32; j++) nf[j] = ob[j];
    float nt0 = cb[0], nt1 = cb[1];
#pragma unroll 1
    for (int c = 0; c < 8; c++) {  // h2 in chunks of 8
        float h2[8];
#pragma unroll
        for (int i = 0; i < 8; i++) h2[i] = b2[c * 8 + i];
#pragma unroll
        for (int k = 0; k < 64; k++) {
            const float* wr = w2 + k * 64 + c * 8;
#pragma unroll
            for (int i = 0; i < 8; i++) h2[i] = fmaf(h1[k], wr[i], h2[i]);
        }
#pragma unroll
        for (int i = 0; i < 8; i++) {
            int kk = c * 8 + i;
#pragma unroll
            for (int j = 0; j < 32; j++) nf[j] = fmaf(h2[i], ow[kk * 32 + j], nf[j]);
            nt0 = fmaf(h2[i], cw[kk * 2 + 0], nt0);
            nt1 = fmaf(h2[i], cw[kk * 2 + 1], nt1);
        }
    }
    float4* o = reinterpret_cast<float4*>(out + (size_t)r * 32);
#pragma unroll
    for (int c = 0; c < 8; c++) {
        o[c] = make_float4(nf[c * 4 + 0], nf[c * 4 + 1], nf[c * 4 + 2], nf[c * 4 + 3]);
    }
    float2* o2 = reinterpret_cast<float2*>(out + (size_t)NN * 32);
    o2[r] = make_float2(nt0, nt1);
}

extern "C" void kernel_launch(void* const* d_in, const int* in_sizes, int n_in,
                              void* d_out, int out_size, void* d_ws, size_t ws_size,
                              hipStream_t stream) {
    const int N = NN, E = EE;
    const float* front_x = (const float*)d_in[0];
    const float* side_x = (const float*)d_in[1];
    const int* fei = (const int*)d_in[2];
    const int* sei = (const int*)d_in[3];
    const float* fe_enc_w1 = (const float*)d_in[4];
    const float* fe_enc_b1 = (const float*)d_in[5];
    const float* fe_enc_w2 = (const float*)d_in[6];
    const float* fe_enc_b2 = (const float*)d_in[7];
    const float* fe_conv_w = (const float*)d_in[8];
    const float* fe_conv_b = (const float*)d_in[9];
    const float* se_enc_w1 = (const float*)d_in[10];
    const float* se_enc_b1 = (const float*)d_in[11];
    const float* se_enc_w2 = (const float*)d_in[12];
    const float* se_enc_b2 = (const float*)d_in[13];
    const float* se_conv_w = (const float*)d_in[14];
    const float* se_conv_b = (const float*)d_in[15];
    const float* fus_w1 = (const float*)d_in[16];
    const float* fus_b1 = (const float*)d_in[17];
    const float* fus_w2 = (const float*)d_in[18];
    const float* fus_b2 = (const float*)d_in[19];
    const float* out_w = (const float*)d_in[20];
    const float* out_b = (const float*)d_in[21];
    const float* cls_w = (const float*)d_in[22];
    const float* cls_b = (const float*)d_in[23];

    // workspace carve (256B aligned)
    char* ws = (char*)d_ws;
    size_t off = 0;
    auto take = [&](size_t bytes) -> char* {
        char* p = ws + off;
        off = (off + bytes + 255) & ~(size_t)255;
        return p;
    };
    int* zb = (int*)take((size_t)2 * N * 4);  // cnt0,cnt1 (zeroed)
    int* cnt0 = zb;
    int* cnt1 = zb + N;
    int* pos0 = (int*)take((size_t)E * 4);
    int* pos1 = (int*)take((size_t)E * 4);
    int* rp0 = (int*)take((size_t)(N + 1) * 4);
    int* rp1 = (int*)take((size_t)(N + 1) * 4);
    float* dv0 = (float*)take((size_t)N * 4);
    float* dv1 = (float*)take((size_t)N * 4);
    int* part0 = (int*)take(256 * 4);
    int* part1 = (int*)take(256 * 4);
    long long* ec0 = (long long*)take((size_t)E * 8);
    long long* ec1 = (long long*)take((size_t)E * 8);
    unsigned short* P0 = (unsigned short*)take((size_t)N * 64 * 2);
    unsigned short* P1 = (unsigned short*)take((size_t)N * 64 * 2);
    unsigned short* Q0 = (unsigned short*)take((size_t)N * 64 * 2);
    unsigned short* Q1 = (unsigned short*)take((size_t)N * 64 * 2);

    const int NB_ROW = (N + 255) / 256;
    const int NB_E = (E + 255) / 256;
    const int NB_C = N / 32;                       // 3125 blocks per graph
    const int GX_C = ((2 * NB_C + 7) / 8) * 8;     // XCD-aligned grid for conv
    const int SB = (N + 1023) / 1024;

    // ---- CSR build for both graphs ----
    hipMemsetAsync(zb, 0, (size_t)2 * N * 4, stream);
    k_count_dual<<<dim3(NB_E, 2), 256, 0, stream>>>(fei + E, sei + E, cnt0, cnt1, pos0, pos1, E);
    k_scan_partial_dual<<<dim3(SB, 2), 256, 0, stream>>>(cnt0, cnt1, part0, part1, dv0, dv1, N);
    k_scan_single_dual<<<dim3(1, 2), 256, 0, stream>>>(part0, part1, SB);
    k_scan_write_dual<<<dim3(SB, 2), 256, 0, stream>>>(cnt0, cnt1, part0, part1, rp0, rp1, N, E);
    k_fill_dual<<<dim3(NB_E, 2), 256, 0, stream>>>(fei, sei, pos0, pos1, dv0, dv1, rp0, rp1,
                                                   (iv2*)ec0, (iv2*)ec1, E);

    // ---- encoders (dual, fused 2-layer MLP) ----
    k_enc_dual<<<dim3(NB_ROW, 2), 256, 0, stream>>>(front_x, side_x, fe_enc_w1, se_enc_w1,
                                                    fe_enc_b1, se_enc_b1, fe_enc_w2, se_enc_w2,
                                                    fe_enc_b2, se_enc_b2, Q0, Q1, N);
    // ---- 3 fused conv layers (XCD-partitioned dual, LDS-staged ec):  Q->P->Q->P ----
    k_conv_dual<<<GX_C, 256, 0, stream>>>(Q0, Q1, ec0, ec1, rp0, rp1, dv0, dv1,
                                          fe_conv_w + 0 * 4096, se_conv_w + 0 * 4096,
                                          fe_conv_b + 0 * 64, se_conv_b + 0 * 64, P0, P1, NB_C);
    k_conv_dual<<<GX_C, 256, 0, stream>>>(P0, P1, ec0, ec1, rp0, rp1, dv0, dv1,
                                          fe_conv_w + 1 * 4096, se_conv_w + 1 * 4096,
                                          fe_conv_b + 1 * 64, se_conv_b + 1 * 64, Q0, Q1, NB_C);
    k_conv_dual<<<GX_C, 256, 0, stream>>>(Q0, Q1, ec0, ec1, rp0, rp1, dv0, dv1,
                                          fe_conv_w + 2 * 4096, se_conv_w + 2 * 4096,
                                          fe_conv_b + 2 * 64, se_conv_b + 2 * 64, P0, P1, NB_C);

    // ---- fused fusion-MLP + heads ----
    k_tail<<<NB_ROW, 256, 0, stream>>>(P0, P1, fus_w1, fus_b1, fus_w2, fus_b2,
                                       out_w, out_b, cls_w, cls_b, (float*)d_out, N);
}